// Round 7
// baseline (3833.854 us; speedup 1.0000x reference)
//
#include <hip/hip_runtime.h>
#include <cmath>

__device__ __forceinline__ float sigm(float x) { return 1.0f / (1.0f + __expf(-x)); }

// ---- merged tiled transposes [2048][K] -> [K][2048], 4 jobs in one launch ----
__global__ __launch_bounds__(256) void transpose_all(
    const float* __restrict__ eWhh, const float* __restrict__ eWih,
    const float* __restrict__ dWhh, const float* __restrict__ dWih,
    float* __restrict__ WTe, float* __restrict__ WTd) {
  __shared__ float tile[32][33];
  const float* in;
  float* outT;
  int K;
  switch (blockIdx.z) {
    case 0: in = eWhh; outT = WTe; K = 512; break;
    case 1: in = eWih; outT = WTe + 512 * 2048; K = 256; break;
    case 2: in = dWhh; outT = WTd; K = 512; break;
    default: in = dWih; outT = WTd + 512 * 2048; K = 256; break;
  }
  int k0 = blockIdx.x * 32;
  if (k0 >= K) return;
  int tx = threadIdx.x & 31, ty = threadIdx.x >> 5;
  int j0 = blockIdx.y * 32;
#pragma unroll
  for (int i = 0; i < 32; i += 8)
    tile[ty + i][tx] = in[(size_t)(j0 + ty + i) * K + k0 + tx];
  __syncthreads();
#pragma unroll
  for (int i = 0; i < 32; i += 8)
    outT[(size_t)(k0 + ty + i) * 2048 + j0 + tx] = tile[tx][ty + i];
}

// one j-slice (32 k values / 8 per thread-kq) of the gate GEMV.
// NOTE: FMA ordering matches R5 exactly; gate accumulation order is numerics-
// critical (chaotic 256-step recurrence) — do NOT split/reorder/restructure
// this source (R6 + this session's R1 both failed on restructure). Pinned.
__device__ __forceinline__ void gemv_j(const float4* __restrict__ A4,
                                       const float4* __restrict__ W4, int j, int kqx,
                                       int kq, int jlo, int jhi, int b0, int b1,
                                       float (&o0)[8], float (&o1)[8]) {
  int qa = (j << 3) + kqx;
  float4 a04 = A4[b0 * 192 + qa];
  float4 a14 = A4[b1 * 192 + qa];
  int wr = ((j << 3) + kq) << 2;  // k base (in rows of W4)
  float a0v[4] = {a04.x, a04.y, a04.z, a04.w};
  float a1v[4] = {a14.x, a14.y, a14.z, a14.w};
#pragma unroll
  for (int i = 0; i < 4; ++i) {
    float4 wlo = W4[(wr + i) * 8 + jlo];
    float4 whi = W4[(wr + i) * 8 + jhi];
    o0[0] = fmaf(a0v[i], wlo.x, o0[0]);
    o0[1] = fmaf(a0v[i], wlo.y, o0[1]);
    o0[2] = fmaf(a0v[i], wlo.z, o0[2]);
    o0[3] = fmaf(a0v[i], wlo.w, o0[3]);
    o0[4] = fmaf(a0v[i], whi.x, o0[4]);
    o0[5] = fmaf(a0v[i], whi.y, o0[5]);
    o0[6] = fmaf(a0v[i], whi.z, o0[6]);
    o0[7] = fmaf(a0v[i], whi.w, o0[7]);
    o1[0] = fmaf(a1v[i], wlo.x, o1[0]);
    o1[1] = fmaf(a1v[i], wlo.y, o1[1]);
    o1[2] = fmaf(a1v[i], wlo.z, o1[2]);
    o1[3] = fmaf(a1v[i], wlo.w, o1[3]);
    o1[4] = fmaf(a1v[i], whi.x, o1[4]);
    o1[5] = fmaf(a1v[i], whi.y, o1[5]);
    o1[6] = fmaf(a1v[i], whi.z, o1[6]);
    o1[7] = fmaf(a1v[i], whi.w, o1[7]);
  }
}

// ---- persistent fused LSTM chain: 256 steps in one cooperative launch ----
// Grid 256 = 4 bg x 64 ng. Block owns 16 batches x 8 hidden units.
// Gate GEMV: single j=0..23 chain (R5 numerics, pinned). Barrier: per-producer
// flags on separate lines (store-only release), wave 0 polls lane-parallel.
// R3 lesson: W belongs in LDS (same-address broadcast dedup beats L2 latency
// at 1 wave/SIMD occupancy) — do not move W to global. Chain is at its
// structural floor (~74% LDS-pipe busy + inherent 64-block sync) — leave it.
__global__ __launch_bounds__(256, 1) void lstm_chain(
    const float* __restrict__ WT, const float* __restrict__ x,
    const float* __restrict__ bih, const float* __restrict__ bhh,
    float* __restrict__ HBUF,        // [256][64][512]
    float* __restrict__ Cst,         // [64][512]
    unsigned int* __restrict__ flg,  // 4 domains x 64 flags x 32 uints
    int is_enc) {
  extern __shared__ float lds[];
  float4* W4 = (float4*)lds;            // 768 x 8 f4 (XOR-swizzled) = 96 KB
  float4* A4 = (float4*)(lds + 24576);  // 16 x 192 f4 (XOR-swizzled) = 48 KB
  float* gates = lds + 24576 + 12288;   // 16 x 40
  const int bg = blockIdx.x >> 6, ng = blockIdx.x & 63;
  const int tid = threadIdx.x;
  unsigned int* myflag = flg + (size_t)(bg * 64 + ng) * 32;
  unsigned int* dom = flg + (size_t)bg * 64 * 32;

  // ---- stage W slice once ----
#pragma unroll
  for (int r = 0; r < 24; ++r) {
    int idx = tid + 256 * r;
    int k = idx >> 3, j = idx & 7;
    float4 v =
        *(const float4*)(WT + (size_t)k * 2048 + (j >> 1) * 512 + ng * 8 + (j & 1) * 4);
    W4[k * 8 + (j ^ ((k >> 2) & 7))] = v;
  }
  // ---- per-thread cell state + biases (threads 0..127 own (b,n8)) ----
  float bi_i = 0.f, bi_f = 0.f, bi_g = 0.f, bi_o = 0.f, creg = 0.f;
  if (tid < 128) {
    int b = tid >> 3, n8 = tid & 7;
    int n_g = ng * 8 + n8;
    bi_i = bih[n_g] + bhh[n_g];
    bi_f = bih[512 + n_g] + bhh[512 + n_g];
    bi_g = bih[1024 + n_g] + bhh[1024 + n_g];
    bi_o = bih[1536 + n_g] + bhh[1536 + n_g];
    if (!is_enc) creg = Cst[(size_t)(bg * 16 + b) * 512 + n_g];
  }
  // ---- initial A-h: h0 (zeros for encoder, HBUF row 255 for decoder) ----
#pragma unroll
  for (int r = 0; r < 8; ++r) {
    int idx = tid + 256 * r;
    int b = idx >> 7, q = idx & 127;
    float4 v;
    if (is_enc)
      v = make_float4(0.f, 0.f, 0.f, 0.f);
    else
      v = *(const float4*)(HBUF + ((size_t)(255 * 64) + bg * 16 + b) * 512 + 4 * q);
    A4[b * 192 + (q ^ ((b >> 1) & 7))] = v;
  }
  // ---- initial A-x: x_0 ----
#pragma unroll
  for (int r = 0; r < 4; ++r) {
    int idx = tid + 256 * r;
    int b = idx >> 6, q = idx & 63;
    float4 v = *(const float4*)(x + ((size_t)(bg * 16 + b) * 256 + 0) * 256 + 4 * q);
    A4[b * 192 + ((128 + q) ^ ((b >> 1) & 7))] = v;
  }
  __syncthreads();

  const int w = tid >> 6;  // wave = gate (0:i 1:f 2:g 3:o)
  const int lane = tid & 63;
  const int kq = lane >> 3, b8 = lane & 7;
  const int b0 = 2 * b8, b1 = b0 + 1;
  const int jlo = (2 * w) ^ kq, jhi = (2 * w + 1) ^ kq;
  const int kqx = kq ^ b8;

  for (int t = 0; t < 256; ++t) {
    float acc0[8], acc1[8];
#pragma unroll
    for (int g = 0; g < 8; ++g) { acc0[g] = 0.f; acc1[g] = 0.f; }
#pragma unroll 2
    for (int j = 0; j < 24; ++j)  // full K=768 chain, R5 order (pinned)
      gemv_j(A4, W4, j, kqx, kq, jlo, jhi, b0, b1, acc0, acc1);
    // reduce over kq (lane-stride 8,16,32)
#pragma unroll
    for (int d = 8; d <= 32; d <<= 1) {
#pragma unroll
      for (int g = 0; g < 8; ++g) {
        acc0[g] += __shfl_xor(acc0[g], d, 64);
        acc1[g] += __shfl_xor(acc1[g], d, 64);
      }
    }
    if (kq == 0) {
#pragma unroll
      for (int g = 0; g < 8; ++g) {
        gates[b0 * 40 + w * 8 + g] = acc0[g];
        gates[b1 * 40 + w * 8 + g] = acc1[g];
      }
    }
    __syncthreads();
    // ---- cell update + h store (agent-scope write-through, no fence) ----
    if (tid < 128) {
      int b = tid >> 3, n8 = tid & 7;
      float pi = gates[b * 40 + n8] + bi_i;
      float pf = gates[b * 40 + 8 + n8] + bi_f;
      float pg = gates[b * 40 + 16 + n8] + bi_g;
      float po = gates[b * 40 + 24 + n8] + bi_o;
      float ig = sigm(pi), fg = sigm(pf), gg = tanhf(pg), og = sigm(po);
      float cn = fmaf(fg, creg, ig * gg);
      if (is_enc) creg = cn;  // decoder: cell pinned at cT
      float hn = og * tanhf(cn);
      float* hp = HBUF + ((size_t)t * 64 + bg * 16 + b) * 512 + ng * 8 + n8;
      __hip_atomic_store(hp, hn, __ATOMIC_RELAXED, __HIP_MEMORY_SCOPE_AGENT);
      if (is_enc && t == 255) Cst[(size_t)(bg * 16 + b) * 512 + ng * 8 + n8] = cn;
    }
    if (t == 255) break;
    // all h of this block at the coherent point before the flag store
    asm volatile("s_waitcnt vmcnt(0)" ::: "memory");
    __syncthreads();
    if (tid == 0)
      __hip_atomic_store(myflag, (unsigned)(t + 1), __ATOMIC_RELAXED,
                         __HIP_MEMORY_SCOPE_AGENT);
    asm volatile("" ::: "memory");  // keep the flag store ahead of the staging
    // ---- stage x_{t+1} (cached, flag-independent) — shadows flag latency ----
#pragma unroll
    for (int r = 0; r < 4; ++r) {
      int idx = tid + 256 * r;
      int b = idx >> 6, q = idx & 63;
      float4 v =
          *(const float4*)(x + ((size_t)(bg * 16 + b) * 256 + (t + 1)) * 256 + 4 * q);
      A4[b * 192 + ((128 + q) ^ ((b >> 1) & 7))] = v;
    }
    // ---- wave 0: poll all 64 producer flags lane-parallel ----
    if (tid < 64) {
      const unsigned tgt = (unsigned)(t + 1);
      unsigned int* fp = dom + (size_t)tid * 32;
      while (true) {
        unsigned v = __hip_atomic_load(fp, __ATOMIC_RELAXED, __HIP_MEMORY_SCOPE_AGENT);
        if (__all((int)(v >= tgt))) break;
        __builtin_amdgcn_s_sleep(1);
      }
    }
    __syncthreads();
    // ---- h restage: plain vectorized loads (first touch after data landed) ----
    const float4* hb = (const float4*)(HBUF + (size_t)t * 64 * 512);
#pragma unroll
    for (int r = 0; r < 8; ++r) {
      int idx = tid + 256 * r;
      int b = idx >> 7, q = idx & 127;
      float4 v = hb[(size_t)(bg * 16 + b) * 128 + q];
      A4[b * 192 + (q ^ ((b >> 1) & 7))] = v;
    }
    __syncthreads();
  }
}

// ---- bf16 MFMA GEMM: C[m,n] = sum_k A[m,k]*W[n,k]; fp32 in, fp32 out ----
// fp32->bf16 RNE conversion fused into LDS staging (no extra buffers/kernels).
// 128x128 tile, 4 waves each 64x64 via 16x16x32 bf16 MFMA. K=512, N=512.
// Output-side only (post-recurrence) — bf16 rounding well under threshold.
typedef __attribute__((ext_vector_type(8))) short bf16x8_t;
typedef __attribute__((ext_vector_type(4))) float f32x4_t;

__device__ __forceinline__ unsigned int pack_bf16_rne(float f0, float f1) {
  unsigned int u0 = __float_as_uint(f0);
  unsigned int u1 = __float_as_uint(f1);
  u0 = (u0 + 0x7FFFu + ((u0 >> 16) & 1u)) >> 16;
  u1 = (u1 + 0x7FFFu + ((u1 >> 16) & 1u)) >> 16;
  return u0 | (u1 << 16);
}

__global__ __launch_bounds__(256) void gemm_bf16(const float* __restrict__ A,
                                                 const float* __restrict__ W,
                                                 float* __restrict__ C) {
  // LDS: [128 rows][40 bf16 stride] (32 used) -> 16B-aligned b128 reads, ~2-way
  __shared__ unsigned short As[128 * 40];
  __shared__ unsigned short Ws[128 * 40];
  int tid = threadIdx.x;
  int n0 = blockIdx.x * 128, m0 = blockIdx.y * 128;
  int wid = tid >> 6, lane = tid & 63;
  int wr = (wid >> 1) * 64, wc = (wid & 1) * 64;  // wave's 64x64 sub-tile
  int l15 = lane & 15, lk = lane >> 4;
  int srow = tid >> 1, shalf = (tid & 1) * 16;  // staging: 16 elems/thread
  f32x4_t acc[4][4];
#pragma unroll
  for (int i = 0; i < 4; ++i)
#pragma unroll
    for (int j = 0; j < 4; ++j) acc[i][j] = (f32x4_t){0.f, 0.f, 0.f, 0.f};

  const float* ap = A + (size_t)(m0 + srow) * 512 + shalf;
  const float* wp = W + (size_t)(n0 + srow) * 512 + shalf;

  for (int k0 = 0; k0 < 512; k0 += 32) {
    float4 av0 = *(const float4*)(ap + k0);
    float4 av1 = *(const float4*)(ap + k0 + 4);
    float4 av2 = *(const float4*)(ap + k0 + 8);
    float4 av3 = *(const float4*)(ap + k0 + 12);
    float4 wv0 = *(const float4*)(wp + k0);
    float4 wv1 = *(const float4*)(wp + k0 + 4);
    float4 wv2 = *(const float4*)(wp + k0 + 8);
    float4 wv3 = *(const float4*)(wp + k0 + 12);
    __syncthreads();  // previous tile's reads done
    {
      uint4 pa0, pa1, pw0, pw1;
      pa0.x = pack_bf16_rne(av0.x, av0.y);
      pa0.y = pack_bf16_rne(av0.z, av0.w);
      pa0.z = pack_bf16_rne(av1.x, av1.y);
      pa0.w = pack_bf16_rne(av1.z, av1.w);
      pa1.x = pack_bf16_rne(av2.x, av2.y);
      pa1.y = pack_bf16_rne(av2.z, av2.w);
      pa1.z = pack_bf16_rne(av3.x, av3.y);
      pa1.w = pack_bf16_rne(av3.z, av3.w);
      pw0.x = pack_bf16_rne(wv0.x, wv0.y);
      pw0.y = pack_bf16_rne(wv0.z, wv0.w);
      pw0.z = pack_bf16_rne(wv1.x, wv1.y);
      pw0.w = pack_bf16_rne(wv1.z, wv1.w);
      pw1.x = pack_bf16_rne(wv2.x, wv2.y);
      pw1.y = pack_bf16_rne(wv2.z, wv2.w);
      pw1.z = pack_bf16_rne(wv3.x, wv3.y);
      pw1.w = pack_bf16_rne(wv3.z, wv3.w);
      *(uint4*)&As[srow * 40 + shalf] = pa0;
      *(uint4*)&As[srow * 40 + shalf + 8] = pa1;
      *(uint4*)&Ws[srow * 40 + shalf] = pw0;
      *(uint4*)&Ws[srow * 40 + shalf + 8] = pw1;
    }
    __syncthreads();
    bf16x8_t af[4], bf[4];
#pragma unroll
    for (int mi = 0; mi < 4; ++mi)
      af[mi] = *(const bf16x8_t*)&As[(wr + mi * 16 + l15) * 40 + lk * 8];
#pragma unroll
    for (int ni = 0; ni < 4; ++ni)
      bf[ni] = *(const bf16x8_t*)&Ws[(wc + ni * 16 + l15) * 40 + lk * 8];
#pragma unroll
    for (int mi = 0; mi < 4; ++mi)
#pragma unroll
      for (int ni = 0; ni < 4; ++ni)
        acc[mi][ni] = __builtin_amdgcn_mfma_f32_16x16x32_bf16(af[mi], bf[ni],
                                                              acc[mi][ni], 0, 0, 0);
  }
  // C/D layout (m89-verified): col = lane&15, row = (lane>>4)*4 + reg
#pragma unroll
  for (int mi = 0; mi < 4; ++mi)
#pragma unroll
    for (int ni = 0; ni < 4; ++ni) {
      float* cp = C + (size_t)(m0 + wr + mi * 16 + lk * 4) * 512 + n0 + wc + ni * 16 + l15;
#pragma unroll
      for (int r = 0; r < 4; ++r) cp[(size_t)r * 512] = acc[mi][ni][r];
    }
}

// ---- fused scorer + log_softmax ----
// Block = (t-tile of 16, b). h2 tile staged once; e1 tiles streamed (same
// aggregate traffic as the old (s-tile,b) layout; inner per-element arithmetic
// identical). Each thread then owns one softmax row's 16 scores in registers
// -> 16-lane shfl max/sum -> write v - mx - lse directly. Kills the separate
// logsoftmax dispatch and its 33 MB out re-read/re-write.
__global__ __launch_bounds__(256) void scorer_fused(const float* __restrict__ E1,
                                                    const float* __restrict__ H2,
                                                    const float* __restrict__ vt,
                                                    float* __restrict__ out) {
  extern __shared__ float smem[];
  float* h2s = smem;         // 16 x 516
  float* e1s = smem + 8256;  // 16 x 516
  const float k2log2e = 2.885390081777927f;  // 2*log2(e)
  int tid = threadIdx.x;
  int tx = blockIdx.x;  // 16 t-tiles of 16
  int b = blockIdx.y;
#pragma unroll
  for (int j = 0; j < 8; ++j) {
    int idx = tid + 256 * j;
    int r = idx >> 7, c4 = idx & 127;
    float4 v = *(const float4*)(H2 + ((size_t)(tx * 16 + r) * 64 + b) * 512 + c4 * 4);
    *(float4*)&h2s[r * 516 + c4 * 4] = v;
  }
  int tl = tid >> 4, sl = tid & 15;
  float score[16];
#pragma unroll 1
  for (int ss = 0; ss < 16; ++ss) {
    __syncthreads();
#pragma unroll
    for (int j = 0; j < 8; ++j) {
      int idx = tid + 256 * j;
      int r = idx >> 7, c4 = idx & 127;
      float4 v = *(const float4*)(E1 + ((size_t)(ss * 16 + r) * 64 + b) * 512 + c4 * 4);
      *(float4*)&e1s[r * 516 + c4 * 4] = v;
    }
    __syncthreads();
    float acc = 0.f;
    const float* ep = &e1s[sl * 516];
    const float* hp = &h2s[tl * 516];
#pragma unroll 8
    for (int w4 = 0; w4 < 128; ++w4) {
      float4 a = *(const float4*)(ep + w4 * 4);
      float4 h = *(const float4*)(hp + w4 * 4);
      float4 vv = *(const float4*)(vt + w4 * 4);
      float x0 = a.x + h.x, x1 = a.y + h.y, x2 = a.z + h.z, x3 = a.w + h.w;
      float t0 = fmaf(-2.f, __builtin_amdgcn_rcpf(__builtin_amdgcn_exp2f(x0 * k2log2e) + 1.f), 1.f);
      float t1 = fmaf(-2.f, __builtin_amdgcn_rcpf(__builtin_amdgcn_exp2f(x1 * k2log2e) + 1.f), 1.f);
      float t2 = fmaf(-2.f, __builtin_amdgcn_rcpf(__builtin_amdgcn_exp2f(x2 * k2log2e) + 1.f), 1.f);
      float t3 = fmaf(-2.f, __builtin_amdgcn_rcpf(__builtin_amdgcn_exp2f(x3 * k2log2e) + 1.f), 1.f);
      acc = fmaf(t0, vv.x, acc);
      acc = fmaf(t1, vv.y, acc);
      acc = fmaf(t2, vv.z, acc);
      acc = fmaf(t3, vv.w, acc);
    }
    score[ss] = acc;  // thread's row t=tx*16+tl, col s=ss*16+sl
  }
  // ---- in-register log_softmax over the row (16 regs x 16 lanes) ----
  float mx = score[0];
#pragma unroll
  for (int i = 1; i < 16; ++i) mx = fmaxf(mx, score[i]);
#pragma unroll
  for (int d = 1; d <= 8; d <<= 1) mx = fmaxf(mx, __shfl_xor(mx, d, 64));
  float sum = 0.f;
#pragma unroll
  for (int i = 0; i < 16; ++i) sum += __expf(score[i] - mx);
#pragma unroll
  for (int d = 1; d <= 8; d <<= 1) sum += __shfl_xor(sum, d, 64);
  float corr = mx + logf(sum);
  float* rowp = out + ((size_t)b * 256 + tx * 16 + tl) * 256 + sl;
#pragma unroll
  for (int ss = 0; ss < 16; ++ss) rowp[ss * 16] = score[ss] - corr;
}

extern "C" void kernel_launch(void* const* d_in, const int* in_sizes, int n_in,
                              void* d_out, int out_size, void* d_ws, size_t ws_size,
                              hipStream_t stream) {
  (void)in_sizes; (void)n_in; (void)out_size; (void)ws_size;
  const float* x = (const float*)d_in[0];
  const float* eWih = (const float*)d_in[1];
  const float* eWhh = (const float*)d_in[2];
  const float* ebih = (const float*)d_in[3];
  const float* ebhh = (const float*)d_in[4];
  const float* dWih = (const float*)d_in[5];
  const float* dWhh = (const float*)d_in[6];
  const float* dbih = (const float*)d_in[7];
  const float* dbhh = (const float*)d_in[8];
  const float* w1 = (const float*)d_in[9];
  const float* w2 = (const float*)d_in[10];
  const float* vt = (const float*)d_in[11];
  float* out = (float*)d_out;
  float* ws = (float*)d_ws;

  // workspace (floats) — ~113.5 MB
  float* E1 = ws;                  //  8,388,608  [S,B,W]
  float* H2 = E1 + 8388608ull;     //  8,388,608  [S,B,W]
  float* HBUF = H2 + 8388608ull;   //  8,388,608  [S,B,H] enc then dec h
  float* WTe = HBUF + 8388608ull;  //  1,572,864  [768][2048]
  float* WTd = WTe + 1572864ull;   //  1,572,864
  float* Cst = WTd + 1572864ull;   //     32,768
  unsigned int* FLG = (unsigned int*)(Cst + 32768ull);  // 2 x 8192 uints (64 KB)

  const unsigned ldsB = (24576 + 12288 + 640) * 4;  // 150,016 B
  const unsigned scorerLds = 2 * 16 * 516 * 4;      // 66,048 B

  hipMemsetAsync(FLG, 0, 16384 * sizeof(unsigned int), stream);
  transpose_all<<<dim3(16, 64, 4), 256, 0, stream>>>(eWhh, eWih, dWhh, dWih, WTe, WTd);

  {  // encoder chain
    const float* a0 = WTe; const float* a1 = x; const float* a2 = ebih;
    const float* a3 = ebhh; float* a4 = HBUF; float* a5 = Cst;
    unsigned int* a6 = FLG; int a7 = 1;
    void* args[] = {&a0, &a1, &a2, &a3, &a4, &a5, &a6, &a7};
    hipLaunchCooperativeKernel((const void*)lstm_chain, dim3(256), dim3(256), args,
                               ldsB, stream);
  }
  gemm_bf16<<<dim3(4, 128), 256, 0, stream>>>(HBUF, w1, E1);
  {  // decoder chain
    const float* a0 = WTd; const float* a1 = x; const float* a2 = dbih;
    const float* a3 = dbhh; float* a4 = HBUF; float* a5 = Cst;
    unsigned int* a6 = FLG + 8192; int a7 = 0;
    void* args[] = {&a0, &a1, &a2, &a3, &a4, &a5, &a6, &a7};
    hipLaunchCooperativeKernel((const void*)lstm_chain, dim3(256), dim3(256), args,
                               ldsB, stream);
  }
  gemm_bf16<<<dim3(4, 128), 256, 0, stream>>>(HBUF, w2, H2);
  scorer_fused<<<dim3(16, 64), 256, scorerLds, stream>>>(E1, H2, vt, out);
}

// Round 9
// 3805.186 us; speedup vs baseline: 1.0075x; 1.0075x over previous
//
#include <hip/hip_runtime.h>
#include <cmath>

__device__ __forceinline__ float sigm(float x) { return 1.0f / (1.0f + __expf(-x)); }

// ---------------- tiled transpose [2048][K] -> [K][2048] ----------------
__global__ __launch_bounds__(256) void transpose_w(const float* __restrict__ in,
                                                   float* __restrict__ outT, int K) {
  __shared__ float tile[32][33];
  int tx = threadIdx.x & 31, ty = threadIdx.x >> 5;
  int k0 = blockIdx.x * 32;
  int j0 = blockIdx.y * 32;
#pragma unroll
  for (int i = 0; i < 32; i += 8)
    tile[ty + i][tx] = in[(size_t)(j0 + ty + i) * K + k0 + tx];
  __syncthreads();
#pragma unroll
  for (int i = 0; i < 32; i += 8)
    outT[(size_t)(k0 + ty + i) * 2048 + j0 + tx] = tile[tx][ty + i];
}

// one j-slice (32 k values / 8 per thread-kq) of the gate GEMV.
// NOTE: FMA ordering matches R5 exactly; gate accumulation order is numerics-
// critical (chaotic 256-step recurrence) — do NOT split/reorder/restructure
// ANYTHING in the chain (R1 global-W, R8 permlane-reduce both failed with the
// identical divergence fingerprint). Source pinned, including the reduce.
__device__ __forceinline__ void gemv_j(const float4* __restrict__ A4,
                                       const float4* __restrict__ W4, int j, int kqx,
                                       int kq, int jlo, int jhi, int b0, int b1,
                                       float (&o0)[8], float (&o1)[8]) {
  int qa = (j << 3) + kqx;
  float4 a04 = A4[b0 * 192 + qa];
  float4 a14 = A4[b1 * 192 + qa];
  int wr = ((j << 3) + kq) << 2;  // k base (in rows of W4)
  float a0v[4] = {a04.x, a04.y, a04.z, a04.w};
  float a1v[4] = {a14.x, a14.y, a14.z, a14.w};
#pragma unroll
  for (int i = 0; i < 4; ++i) {
    float4 wlo = W4[(wr + i) * 8 + jlo];
    float4 whi = W4[(wr + i) * 8 + jhi];
    o0[0] = fmaf(a0v[i], wlo.x, o0[0]);
    o0[1] = fmaf(a0v[i], wlo.y, o0[1]);
    o0[2] = fmaf(a0v[i], wlo.z, o0[2]);
    o0[3] = fmaf(a0v[i], wlo.w, o0[3]);
    o0[4] = fmaf(a0v[i], whi.x, o0[4]);
    o0[5] = fmaf(a0v[i], whi.y, o0[5]);
    o0[6] = fmaf(a0v[i], whi.z, o0[6]);
    o0[7] = fmaf(a0v[i], whi.w, o0[7]);
    o1[0] = fmaf(a1v[i], wlo.x, o1[0]);
    o1[1] = fmaf(a1v[i], wlo.y, o1[1]);
    o1[2] = fmaf(a1v[i], wlo.z, o1[2]);
    o1[3] = fmaf(a1v[i], wlo.w, o1[3]);
    o1[4] = fmaf(a1v[i], whi.x, o1[4]);
    o1[5] = fmaf(a1v[i], whi.y, o1[5]);
    o1[6] = fmaf(a1v[i], whi.z, o1[6]);
    o1[7] = fmaf(a1v[i], whi.w, o1[7]);
  }
}

// ---- persistent fused LSTM chain: 256 steps in one cooperative launch ----
// Grid 256 = 4 bg x 64 ng. Block owns 16 batches x 8 hidden units.
// Gate GEMV: single j=0..23 chain (R5 numerics, pinned). Barrier: per-producer
// flags on separate lines (store-only release), wave 0 polls lane-parallel.
// Structural floor: LDS pipe ~74% busy (pinned broadcast reads) + inherent
// 64-block sync. All modification attempts (W->global, permlane reduce)
// perturb the chaotic recurrence — chain is final.
__global__ __launch_bounds__(256, 1) void lstm_chain(
    const float* __restrict__ WT, const float* __restrict__ x,
    const float* __restrict__ bih, const float* __restrict__ bhh,
    float* __restrict__ HBUF,        // [256][64][512]
    float* __restrict__ Cst,         // [64][512]
    unsigned int* __restrict__ flg,  // 4 domains x 64 flags x 32 uints
    int is_enc) {
  extern __shared__ float lds[];
  float4* W4 = (float4*)lds;            // 768 x 8 f4 (XOR-swizzled) = 96 KB
  float4* A4 = (float4*)(lds + 24576);  // 16 x 192 f4 (XOR-swizzled) = 48 KB
  float* gates = lds + 24576 + 12288;   // 16 x 40
  const int bg = blockIdx.x >> 6, ng = blockIdx.x & 63;
  const int tid = threadIdx.x;
  unsigned int* myflag = flg + (size_t)(bg * 64 + ng) * 32;
  unsigned int* dom = flg + (size_t)bg * 64 * 32;

  // ---- stage W slice once ----
#pragma unroll
  for (int r = 0; r < 24; ++r) {
    int idx = tid + 256 * r;
    int k = idx >> 3, j = idx & 7;
    float4 v =
        *(const float4*)(WT + (size_t)k * 2048 + (j >> 1) * 512 + ng * 8 + (j & 1) * 4);
    W4[k * 8 + (j ^ ((k >> 2) & 7))] = v;
  }
  // ---- per-thread cell state + biases (threads 0..127 own (b,n8)) ----
  float bi_i = 0.f, bi_f = 0.f, bi_g = 0.f, bi_o = 0.f, creg = 0.f;
  if (tid < 128) {
    int b = tid >> 3, n8 = tid & 7;
    int n_g = ng * 8 + n8;
    bi_i = bih[n_g] + bhh[n_g];
    bi_f = bih[512 + n_g] + bhh[512 + n_g];
    bi_g = bih[1024 + n_g] + bhh[1024 + n_g];
    bi_o = bih[1536 + n_g] + bhh[1536 + n_g];
    if (!is_enc) creg = Cst[(size_t)(bg * 16 + b) * 512 + n_g];
  }
  // ---- initial A-h: h0 (zeros for encoder, HBUF row 255 for decoder) ----
#pragma unroll
  for (int r = 0; r < 8; ++r) {
    int idx = tid + 256 * r;
    int b = idx >> 7, q = idx & 127;
    float4 v;
    if (is_enc)
      v = make_float4(0.f, 0.f, 0.f, 0.f);
    else
      v = *(const float4*)(HBUF + ((size_t)(255 * 64) + bg * 16 + b) * 512 + 4 * q);
    A4[b * 192 + (q ^ ((b >> 1) & 7))] = v;
  }
  // ---- initial A-x: x_0 ----
#pragma unroll
  for (int r = 0; r < 4; ++r) {
    int idx = tid + 256 * r;
    int b = idx >> 6, q = idx & 63;
    float4 v = *(const float4*)(x + ((size_t)(bg * 16 + b) * 256 + 0) * 256 + 4 * q);
    A4[b * 192 + ((128 + q) ^ ((b >> 1) & 7))] = v;
  }
  __syncthreads();

  const int w = tid >> 6;  // wave = gate (0:i 1:f 2:g 3:o)
  const int lane = tid & 63;
  const int kq = lane >> 3, b8 = lane & 7;
  const int b0 = 2 * b8, b1 = b0 + 1;
  const int jlo = (2 * w) ^ kq, jhi = (2 * w + 1) ^ kq;
  const int kqx = kq ^ b8;

  for (int t = 0; t < 256; ++t) {
    float acc0[8], acc1[8];
#pragma unroll
    for (int g = 0; g < 8; ++g) { acc0[g] = 0.f; acc1[g] = 0.f; }
#pragma unroll 2
    for (int j = 0; j < 24; ++j)  // full K=768 chain, R5 order (pinned)
      gemv_j(A4, W4, j, kqx, kq, jlo, jhi, b0, b1, acc0, acc1);
    // reduce over kq (lane-stride 8,16,32) — pinned form
#pragma unroll
    for (int d = 8; d <= 32; d <<= 1) {
#pragma unroll
      for (int g = 0; g < 8; ++g) {
        acc0[g] += __shfl_xor(acc0[g], d, 64);
        acc1[g] += __shfl_xor(acc1[g], d, 64);
      }
    }
    if (kq == 0) {
#pragma unroll
      for (int g = 0; g < 8; ++g) {
        gates[b0 * 40 + w * 8 + g] = acc0[g];
        gates[b1 * 40 + w * 8 + g] = acc1[g];
      }
    }
    __syncthreads();
    // ---- cell update + h store (agent-scope write-through, no fence) ----
    if (tid < 128) {
      int b = tid >> 3, n8 = tid & 7;
      float pi = gates[b * 40 + n8] + bi_i;
      float pf = gates[b * 40 + 8 + n8] + bi_f;
      float pg = gates[b * 40 + 16 + n8] + bi_g;
      float po = gates[b * 40 + 24 + n8] + bi_o;
      float ig = sigm(pi), fg = sigm(pf), gg = tanhf(pg), og = sigm(po);
      float cn = fmaf(fg, creg, ig * gg);
      if (is_enc) creg = cn;  // decoder: cell pinned at cT
      float hn = og * tanhf(cn);
      float* hp = HBUF + ((size_t)t * 64 + bg * 16 + b) * 512 + ng * 8 + n8;
      __hip_atomic_store(hp, hn, __ATOMIC_RELAXED, __HIP_MEMORY_SCOPE_AGENT);
      if (is_enc && t == 255) Cst[(size_t)(bg * 16 + b) * 512 + ng * 8 + n8] = cn;
    }
    if (t == 255) break;
    // all h of this block at the coherent point before the flag store
    asm volatile("s_waitcnt vmcnt(0)" ::: "memory");
    __syncthreads();
    if (tid == 0)
      __hip_atomic_store(myflag, (unsigned)(t + 1), __ATOMIC_RELAXED,
                         __HIP_MEMORY_SCOPE_AGENT);
    asm volatile("" ::: "memory");  // keep the flag store ahead of the staging
    // ---- stage x_{t+1} (cached, flag-independent) — shadows flag latency ----
#pragma unroll
    for (int r = 0; r < 4; ++r) {
      int idx = tid + 256 * r;
      int b = idx >> 6, q = idx & 63;
      float4 v =
          *(const float4*)(x + ((size_t)(bg * 16 + b) * 256 + (t + 1)) * 256 + 4 * q);
      A4[b * 192 + ((128 + q) ^ ((b >> 1) & 7))] = v;
    }
    // ---- wave 0: poll all 64 producer flags lane-parallel ----
    if (tid < 64) {
      const unsigned tgt = (unsigned)(t + 1);
      unsigned int* fp = dom + (size_t)tid * 32;
      while (true) {
        unsigned v = __hip_atomic_load(fp, __ATOMIC_RELAXED, __HIP_MEMORY_SCOPE_AGENT);
        if (__all((int)(v >= tgt))) break;
        __builtin_amdgcn_s_sleep(1);
      }
    }
    __syncthreads();
    // ---- h restage: plain vectorized loads (first touch after data landed) ----
    const float4* hb = (const float4*)(HBUF + (size_t)t * 64 * 512);
#pragma unroll
    for (int r = 0; r < 8; ++r) {
      int idx = tid + 256 * r;
      int b = idx >> 7, q = idx & 127;
      float4 v = hb[(size_t)(bg * 16 + b) * 128 + q];
      A4[b * 192 + (q ^ ((b >> 1) & 7))] = v;
    }
    __syncthreads();
  }
}

// ---- bf16 MFMA GEMM: C[m,n] = sum_k A[m,k]*W[n,k]; fp32 in, fp32 out ----
// fp32->bf16 RNE conversion fused into LDS staging (no extra buffers/kernels).
// 128x128 tile, 4 waves each 64x64 via 16x16x32 bf16 MFMA. K=512, N=512.
// Output-side only (post-recurrence) — bf16 rounding well under threshold.
typedef __attribute__((ext_vector_type(8))) short bf16x8_t;
typedef __attribute__((ext_vector_type(4))) float f32x4_t;

__device__ __forceinline__ unsigned int pack_bf16_rne(float f0, float f1) {
  unsigned int u0 = __float_as_uint(f0);
  unsigned int u1 = __float_as_uint(f1);
  u0 = (u0 + 0x7FFFu + ((u0 >> 16) & 1u)) >> 16;
  u1 = (u1 + 0x7FFFu + ((u1 >> 16) & 1u)) >> 16;
  return u0 | (u1 << 16);
}

__global__ __launch_bounds__(256) void gemm_bf16(const float* __restrict__ A,
                                                 const float* __restrict__ W,
                                                 float* __restrict__ C) {
  // LDS: [128 rows][40 bf16 stride] (32 used) -> 16B-aligned b128 reads, ~2-way
  __shared__ unsigned short As[128 * 40];
  __shared__ unsigned short Ws[128 * 40];
  int tid = threadIdx.x;
  int n0 = blockIdx.x * 128, m0 = blockIdx.y * 128;
  int wid = tid >> 6, lane = tid & 63;
  int wr = (wid >> 1) * 64, wc = (wid & 1) * 64;  // wave's 64x64 sub-tile
  int l15 = lane & 15, lk = lane >> 4;
  int srow = tid >> 1, shalf = (tid & 1) * 16;  // staging: 16 elems/thread
  f32x4_t acc[4][4];
#pragma unroll
  for (int i = 0; i < 4; ++i)
#pragma unroll
    for (int j = 0; j < 4; ++j) acc[i][j] = (f32x4_t){0.f, 0.f, 0.f, 0.f};

  const float* ap = A + (size_t)(m0 + srow) * 512 + shalf;
  const float* wp = W + (size_t)(n0 + srow) * 512 + shalf;

  for (int k0 = 0; k0 < 512; k0 += 32) {
    float4 av0 = *(const float4*)(ap + k0);
    float4 av1 = *(const float4*)(ap + k0 + 4);
    float4 av2 = *(const float4*)(ap + k0 + 8);
    float4 av3 = *(const float4*)(ap + k0 + 12);
    float4 wv0 = *(const float4*)(wp + k0);
    float4 wv1 = *(const float4*)(wp + k0 + 4);
    float4 wv2 = *(const float4*)(wp + k0 + 8);
    float4 wv3 = *(const float4*)(wp + k0 + 12);
    __syncthreads();  // previous tile's reads done
    {
      uint4 pa0, pa1, pw0, pw1;
      pa0.x = pack_bf16_rne(av0.x, av0.y);
      pa0.y = pack_bf16_rne(av0.z, av0.w);
      pa0.z = pack_bf16_rne(av1.x, av1.y);
      pa0.w = pack_bf16_rne(av1.z, av1.w);
      pa1.x = pack_bf16_rne(av2.x, av2.y);
      pa1.y = pack_bf16_rne(av2.z, av2.w);
      pa1.z = pack_bf16_rne(av3.x, av3.y);
      pa1.w = pack_bf16_rne(av3.z, av3.w);
      pw0.x = pack_bf16_rne(wv0.x, wv0.y);
      pw0.y = pack_bf16_rne(wv0.z, wv0.w);
      pw0.z = pack_bf16_rne(wv1.x, wv1.y);
      pw0.w = pack_bf16_rne(wv1.z, wv1.w);
      pw1.x = pack_bf16_rne(wv2.x, wv2.y);
      pw1.y = pack_bf16_rne(wv2.z, wv2.w);
      pw1.z = pack_bf16_rne(wv3.x, wv3.y);
      pw1.w = pack_bf16_rne(wv3.z, wv3.w);
      *(uint4*)&As[srow * 40 + shalf] = pa0;
      *(uint4*)&As[srow * 40 + shalf + 8] = pa1;
      *(uint4*)&Ws[srow * 40 + shalf] = pw0;
      *(uint4*)&Ws[srow * 40 + shalf + 8] = pw1;
    }
    __syncthreads();
    bf16x8_t af[4], bf[4];
#pragma unroll
    for (int mi = 0; mi < 4; ++mi)
      af[mi] = *(const bf16x8_t*)&As[(wr + mi * 16 + l15) * 40 + lk * 8];
#pragma unroll
    for (int ni = 0; ni < 4; ++ni)
      bf[ni] = *(const bf16x8_t*)&Ws[(wc + ni * 16 + l15) * 40 + lk * 8];
#pragma unroll
    for (int mi = 0; mi < 4; ++mi)
#pragma unroll
      for (int ni = 0; ni < 4; ++ni)
        acc[mi][ni] = __builtin_amdgcn_mfma_f32_16x16x32_bf16(af[mi], bf[ni],
                                                              acc[mi][ni], 0, 0, 0);
  }
  // C/D layout (m89-verified): col = lane&15, row = (lane>>4)*4 + reg
#pragma unroll
  for (int mi = 0; mi < 4; ++mi)
#pragma unroll
    for (int ni = 0; ni < 4; ++ni) {
      float* cp = C + (size_t)(m0 + wr + mi * 16 + lk * 4) * 512 + n0 + wc + ni * 16 + l15;
#pragma unroll
      for (int r = 0; r < 4; ++r) cp[(size_t)r * 512] = acc[mi][ni][r];
    }
}

// ---- scorer: out[b,t,s] = sum_w vt[w]*tanh(e1[s,b,w] + H2[t,b,w]) ----
// 256 threads, 16x16 (t,s) tile, dynamic LDS 66 KB -> 2 blocks/CU, 8 waves/CU.
// tanh folded to 1 - 2/(exp2(x*2log2e)+1) — trans-pipe bound (~2.1e9 evals).
__global__ __launch_bounds__(256) void scorer(const float* __restrict__ E1,
                                              const float* __restrict__ H2,
                                              const float* __restrict__ vt,
                                              float* __restrict__ out) {
  extern __shared__ float smem[];
  float* e1s = smem;         // 16 x 516
  float* h2s = smem + 8256;  // 16 x 516
  const float k2log2e = 2.885390081777927f;  // 2*log2(e)
  int tid = threadIdx.x;
  int sx = blockIdx.x;  // 16 s-tiles of 16
  int b = blockIdx.y;
#pragma unroll
  for (int j = 0; j < 8; ++j) {
    int idx = tid + 256 * j;
    int r = idx >> 7, c4 = idx & 127;
    float4 v = *(const float4*)(E1 + ((size_t)(sx * 16 + r) * 64 + b) * 512 + c4 * 4);
    *(float4*)&e1s[r * 516 + c4 * 4] = v;
  }
  int tl = tid >> 4, sl = tid & 15;
  for (int tt = 0; tt < 16; ++tt) {
    __syncthreads();
#pragma unroll
    for (int j = 0; j < 8; ++j) {
      int idx = tid + 256 * j;
      int r = idx >> 7, c4 = idx & 127;
      float4 v = *(const float4*)(H2 + ((size_t)(tt * 16 + r) * 64 + b) * 512 + c4 * 4);
      *(float4*)&h2s[r * 516 + c4 * 4] = v;
    }
    __syncthreads();
    float acc = 0.f;
    const float* ep = &e1s[sl * 516];
    const float* hp = &h2s[tl * 516];
#pragma unroll 8
    for (int w4 = 0; w4 < 128; ++w4) {
      float4 a = *(const float4*)(ep + w4 * 4);
      float4 h = *(const float4*)(hp + w4 * 4);
      float4 vv = *(const float4*)(vt + w4 * 4);
      float x0 = a.x + h.x, x1 = a.y + h.y, x2 = a.z + h.z, x3 = a.w + h.w;
      float t0 = fmaf(-2.f, __builtin_amdgcn_rcpf(__builtin_amdgcn_exp2f(x0 * k2log2e) + 1.f), 1.f);
      float t1 = fmaf(-2.f, __builtin_amdgcn_rcpf(__builtin_amdgcn_exp2f(x1 * k2log2e) + 1.f), 1.f);
      float t2 = fmaf(-2.f, __builtin_amdgcn_rcpf(__builtin_amdgcn_exp2f(x2 * k2log2e) + 1.f), 1.f);
      float t3 = fmaf(-2.f, __builtin_amdgcn_rcpf(__builtin_amdgcn_exp2f(x3 * k2log2e) + 1.f), 1.f);
      acc = fmaf(t0, vv.x, acc);
      acc = fmaf(t1, vv.y, acc);
      acc = fmaf(t2, vv.z, acc);
      acc = fmaf(t3, vv.w, acc);
    }
    out[((size_t)b * 256 + tt * 16 + tl) * 256 + sx * 16 + sl] = acc;
  }
}

// ---- in-place log_softmax over rows of 256: wave shuffles, 2 barriers ----
__global__ __launch_bounds__(256) void logsoftmax_kernel(float* __restrict__ out) {
  __shared__ float red[8];
  int tid = threadIdx.x;
  int wv = tid >> 6, ln = tid & 63;
  float* row = out + (size_t)blockIdx.x * 256;
  float v = row[tid];
  float m = v;
#pragma unroll
  for (int d = 1; d <= 32; d <<= 1) m = fmaxf(m, __shfl_xor(m, d, 64));
  if (ln == 0) red[wv] = m;
  __syncthreads();
  float mx = fmaxf(fmaxf(red[0], red[1]), fmaxf(red[2], red[3]));
  float e = __expf(v - mx);
  float s = e;
#pragma unroll
  for (int d = 1; d <= 32; d <<= 1) s += __shfl_xor(s, d, 64);
  if (ln == 0) red[4 + wv] = s;
  __syncthreads();
  float lse = logf((red[4] + red[5]) + (red[6] + red[7]));
  row[tid] = v - mx - lse;
}

extern "C" void kernel_launch(void* const* d_in, const int* in_sizes, int n_in,
                              void* d_out, int out_size, void* d_ws, size_t ws_size,
                              hipStream_t stream) {
  (void)in_sizes; (void)n_in; (void)out_size; (void)ws_size;
  const float* x = (const float*)d_in[0];
  const float* eWih = (const float*)d_in[1];
  const float* eWhh = (const float*)d_in[2];
  const float* ebih = (const float*)d_in[3];
  const float* ebhh = (const float*)d_in[4];
  const float* dWih = (const float*)d_in[5];
  const float* dWhh = (const float*)d_in[6];
  const float* dbih = (const float*)d_in[7];
  const float* dbhh = (const float*)d_in[8];
  const float* w1 = (const float*)d_in[9];
  const float* w2 = (const float*)d_in[10];
  const float* vt = (const float*)d_in[11];
  float* out = (float*)d_out;
  float* ws = (float*)d_ws;

  // workspace (floats) — ~113.5 MB
  float* E1 = ws;                  //  8,388,608  [S,B,W]
  float* H2 = E1 + 8388608ull;     //  8,388,608  [S,B,W]
  float* HBUF = H2 + 8388608ull;   //  8,388,608  [S,B,H] enc then dec h
  float* WTe = HBUF + 8388608ull;  //  1,572,864  [768][2048]
  float* WTd = WTe + 1572864ull;   //  1,572,864
  float* Cst = WTd + 1572864ull;   //     32,768
  unsigned int* FLG = (unsigned int*)(Cst + 32768ull);  // 2 x 8192 uints (64 KB)

  const unsigned ldsB = (24576 + 12288 + 640) * 4;  // 150,016 B
  const unsigned scorerLds = 2 * 16 * 516 * 4;      // 66,048 B

  hipMemsetAsync(FLG, 0, 16384 * sizeof(unsigned int), stream);
  transpose_w<<<dim3(16, 64), 256, 0, stream>>>(eWhh, WTe, 512);
  transpose_w<<<dim3(8, 64), 256, 0, stream>>>(eWih, WTe + 512 * 2048, 256);
  transpose_w<<<dim3(16, 64), 256, 0, stream>>>(dWhh, WTd, 512);
  transpose_w<<<dim3(8, 64), 256, 0, stream>>>(dWih, WTd + 512 * 2048, 256);

  {  // encoder chain
    const float* a0 = WTe; const float* a1 = x; const float* a2 = ebih;
    const float* a3 = ebhh; float* a4 = HBUF; float* a5 = Cst;
    unsigned int* a6 = FLG; int a7 = 1;
    void* args[] = {&a0, &a1, &a2, &a3, &a4, &a5, &a6, &a7};
    hipLaunchCooperativeKernel((const void*)lstm_chain, dim3(256), dim3(256), args,
                               ldsB, stream);
  }
  gemm_bf16<<<dim3(4, 128), 256, 0, stream>>>(HBUF, w1, E1);
  {  // decoder chain
    const float* a0 = WTd; const float* a1 = x; const float* a2 = dbih;
    const float* a3 = dbhh; float* a4 = HBUF; float* a5 = Cst;
    unsigned int* a6 = FLG + 8192; int a7 = 0;
    void* args[] = {&a0, &a1, &a2, &a3, &a4, &a5, &a6, &a7};
    hipLaunchCooperativeKernel((const void*)lstm_chain, dim3(256), dim3(256), args,
                               ldsB, stream);
  }
  gemm_bf16<<<dim3(4, 128), 256, 0, stream>>>(HBUF, w2, H2);
  scorer<<<dim3(16, 64), 256, scorerLds, stream>>>(E1, H2, vt, out);
  logsoftmax_kernel<<<16384, 256, 0, stream>>>(out);
}